// Round 1
// baseline (29055.890 us; speedup 1.0000x reference)
//
#include <hip/hip_runtime.h>
#include <math.h>

// UKF, one block per trajectory, 256 threads, all state in LDS.
// n=64 states, m=32 obs, T=250 steps, 128 trajectories.
// Weights: lam=-1, n+lam=63: Wm0=-1/63, Wc0=2-1/63, rest 0.5/63.

#define NTRAJ 128
#define TSTEPS 250
#define NS 64
#define NO 32
#define PS 66    // P (and Pn) row stride: 2-way conflict max on column access
#define SFS 68   // sigma buffer row stride: multiple of 4 -> float4-aligned rows
#define HS 66    // H row stride
#define PXS 33   // Pxz / K row stride: conflict-free column access
#define GJS 66   // Gauss-Jordan workspace / M stride
#define BLK 256

#define DTc 0.02f
#define W_C (0.5f/63.0f)
#define WM0 (-1.0f/63.0f)
#define WC0 (2.0f - 1.0f/63.0f)

__global__ __launch_bounds__(BLK)
void ukf_main(const float* __restrict__ Xg, const float* __restrict__ Yg,
              const float* __restrict__ Fg, const float* __restrict__ Hg,
              const float* __restrict__ Qg, const float* __restrict__ Rg,
              float* __restrict__ outX, float* __restrict__ outP,
              float* __restrict__ wsPart)
{
  __shared__ __align__(16) float P[NS*PS];      // 4224 floats: P / chol L / Pn / P_new
  __shared__ __align__(16) float sfb[128*SFS];  // 8704 floats: F^T + FL + sigma pts; overlaid below
  __shared__ float sH[NO*HS];                   // 2112
  __shared__ float sPart[4*NS];                 // 256
  __shared__ float sx[NS], sxp[NS], sFx[NS], s0[NS];
  __shared__ float sinn[NO], colp[NO];

  float* Pxz = sfb;                 // [0,    2112): 64 x PXS
  float* Km  = sfb + NS*PXS;        // [2112, 4224): 64 x PXS
  float* Wgj = sfb + 2*NS*PXS;      // [4224, 6336): 32 x GJS  (GJ workspace [Pz | I])
  float* Mb  = sfb + 2*NS*PXS;      // [4224, 8448): 64 x GJS  (M, after GJ is dead)

  const int tid  = threadIdx.x;
  const int lane = tid & 63;
  const int grp  = tid >> 6;
  const int traj = blockIdx.x;

  // ---- one-time init: P = 1e-5*I, x = 0, stage H (row stride HS)
  for (int o = tid; o < NS*NS; o += BLK) {
    int i = o >> 6, j = o & 63;
    P[i*PS + j] = (i == j) ? 1e-5f : 0.f;
  }
  for (int o = tid; o < NO*NS; o += BLK) {
    int m = o >> 6, j = o & 63;
    sH[m*HS + j] = Hg[o];
  }
  if (tid < NS) sx[tid] = 0.f;
  float errAcc = 0.f;
  __syncthreads();

  for (int t = 0; t < TSTEPS; ++t) {
    const size_t sbase = (size_t)traj*TSTEPS + t;

    // ---- phase 1: A = 63*(P + 1e-8 I) in place; stage F^T into sfb rows 0..63
    for (int o = tid; o < NS*NS; o += BLK) {
      int i = o >> 6, j = o & 63;
      float v = P[i*PS + j] * 63.f;
      if (i == j) v += 63e-8f;
      P[i*PS + j] = v;
      sfb[j*SFS + i] = Fg[o];     // FT[jj][j] = F[j][jj]
    }
    __syncthreads();

    // ---- phase 2: Cholesky column 0 (wave0, lock-step)
    if (tid < NS) {
      float d = sqrtf(P[0]);
      float v = P[tid*PS];
      P[tid*PS] = (tid == 0) ? d : v / d;
    }
    __syncthreads();

    // ---- phase 3: Cholesky, 1 barrier per column.
    // wave0: apply rank-1 (col j) to column j+1 and scale it.
    // waves 1-3: apply rank-1 (col j) to trailing cols >= j+2 (lower triangle).
    for (int j = 0; j < NS-1; ++j) {
      if (grp == 0) {
        int i = lane;
        float lj  = P[(j+1)*PS + j];
        float pij = P[i*PS + j];
        float v = P[i*PS + (j+1)] - pij * lj;
        float dv = __shfl(v, j+1);
        float d = sqrtf(dv);
        if (i >= j+1) P[i*PS + (j+1)] = (i == j+1) ? d : v / d;
      } else {
        int s = NS - 2 - j;                 // trailing size
        int cnt = (s*(s+1)) >> 1;
        for (int e = tid - 64; e < cnt; e += 192) {
          float fe = (float)e;
          int a = (int)((sqrtf(8.f*fe + 1.f) - 1.f) * 0.5f);
          while ((a+1)*(a+2)/2 <= e) ++a;
          while (a*(a+1)/2 > e) --a;
          int b = e - ((a*(a+1)) >> 1);
          int i = j + 2 + a, k = j + 2 + b;
          P[i*PS + k] -= P[i*PS + j] * P[k*PS + j];
        }
      }
      __syncthreads();
    }

    // ---- phase 4: FL = F @ L into sfb rows 64..127 (row 64+c holds FL[:,c]); Fx
    {
      const int c0 = (tid >> 4) << 2;
      const int j0 = (tid & 15) << 2;
      float acc[4][4];
      #pragma unroll
      for (int a = 0; a < 4; ++a)
        #pragma unroll
        for (int b = 0; b < 4; ++b) acc[a][b] = 0.f;
      for (int jj = 0; jj < NS; ++jj) {
        float4 fv = *(const float4*)&sfb[jj*SFS + j0];  // FT[jj][j0..j0+3]
        float lv[4];
        #pragma unroll
        for (int a = 0; a < 4; ++a) {
          int c = c0 + a;
          lv[a] = (jj >= c) ? P[jj*PS + c] : 0.f;       // L[jj][c]
        }
        #pragma unroll
        for (int a = 0; a < 4; ++a) {
          acc[a][0] += lv[a]*fv.x; acc[a][1] += lv[a]*fv.y;
          acc[a][2] += lv[a]*fv.z; acc[a][3] += lv[a]*fv.w;
        }
      }
      #pragma unroll
      for (int a = 0; a < 4; ++a) {
        float4 w; w.x = acc[a][0]; w.y = acc[a][1]; w.z = acc[a][2]; w.w = acc[a][3];
        *(float4*)&sfb[(64 + c0 + a)*SFS + j0] = w;     // FL[j][c] at sfb[64+c][j]
      }
    }
    if (tid < NS) {            // Fx = F @ x (reads FT rows, untouched this phase)
      float a2 = 0.f;
      for (int jj = 0; jj < NS; ++jj) a2 += sfb[jj*SFS + tid] * sx[jj];
      sFx[tid] = a2;
    }
    __syncthreads();

    // ---- phase 5: transform -> sigma points. rows 0..63 = plus, 64..127 = minus, s0 = center
    for (int cc = grp; cc < NS; cc += 4) {
      int j = lane;
      float flv = sfb[(64+cc)*SFS + j];
      float Lv  = (j >= cc) ? P[j*PS + cc] : 0.f;
      float xv = sx[j], fxv = sFx[j];
      sfb[cc*SFS + j]      = xv + Lv + DTc * tanhf(fxv + flv);
      sfb[(64+cc)*SFS + j] = xv - Lv + DTc * tanhf(fxv - flv);
    }
    if (tid < NS) s0[tid] = sx[tid] + DTc * tanhf(sFx[tid]);
    __syncthreads();

    // ---- phase 6: x_pred partial sums (each group sums 32 rows)
    {
      float a2 = 0.f;
      int rbeg = grp*32;
      for (int r = rbeg; r < rbeg+32; ++r) a2 += sfb[r*SFS + lane];
      sPart[grp*NS + lane] = a2;
    }
    __syncthreads();
    // ---- phase 7: combine + center deviation d0 (in s0)
    if (tid < NS) {
      float xp = WM0*s0[tid] + W_C*(sPart[tid] + sPart[NS+tid] + sPart[2*NS+tid] + sPart[3*NS+tid]);
      sxp[tid] = xp;
      s0[tid] -= xp;
    }
    __syncthreads();
    // ---- phase 8: dxs in place
    for (int o = tid; o < 128*NS; o += BLK) {
      int r = o >> 6, j = o & 63;
      sfb[r*SFS + j] -= sxp[j];
    }
    __syncthreads();

    // ---- phase 9: Pn = Wc0*d0 d0^T + c * sum_k dxs dxs^T  -> P (4x4 register tiles)
    {
      const int i0 = (tid >> 4) << 2;
      const int j0 = (tid & 15) << 2;
      float acc[4][4];
      #pragma unroll
      for (int a = 0; a < 4; ++a)
        #pragma unroll
        for (int b = 0; b < 4; ++b) acc[a][b] = 0.f;
      for (int r = 0; r < 128; ++r) {
        float4 av = *(const float4*)&sfb[r*SFS + i0];
        float4 bv = *(const float4*)&sfb[r*SFS + j0];
        float aa[4] = {av.x, av.y, av.z, av.w};
        float bb[4] = {bv.x, bv.y, bv.z, bv.w};
        #pragma unroll
        for (int a = 0; a < 4; ++a)
          #pragma unroll
          for (int b = 0; b < 4; ++b) acc[a][b] += aa[a]*bb[b];
      }
      #pragma unroll
      for (int a = 0; a < 4; ++a) {
        float d0a = s0[i0+a];
        #pragma unroll
        for (int b = 0; b < 4; ++b)
          P[(i0+a)*PS + (j0+b)] = WC0 * d0a * s0[j0+b] + W_C * acc[a][b];
      }
    }
    __syncthreads();

    // ---- phase 10: Pxz = Pn @ H^T (64 x 32)
    {
      int i = lane;
      float acc[8];
      #pragma unroll
      for (int q = 0; q < 8; ++q) acc[q] = 0.f;
      for (int jj = 0; jj < NS; ++jj) {
        float pv = P[i*PS + jj];
        #pragma unroll
        for (int q = 0; q < 8; ++q) acc[q] += pv * sH[(grp + 4*q)*HS + jj];
      }
      #pragma unroll
      for (int q = 0; q < 8; ++q) Pxz[i*PXS + (grp + 4*q)] = acc[q];
    }
    __syncthreads();

    // ---- phase 11: Pz = H @ Pxz + R -> GJ workspace [Pz | I]
    for (int o = tid; o < NO*NO; o += BLK) {
      int m = o >> 5, n = o & 31;
      float acc = Rg[o];
      for (int i2 = 0; i2 < NS; ++i2) acc += sH[m*HS + i2] * Pxz[i2*PXS + n];
      Wgj[m*GJS + n] = acc;
      Wgj[m*GJS + NO + n] = (m == n) ? 1.f : 0.f;
    }
    __syncthreads();

    // ---- Gauss-Jordan inverse of Pz (SPD, no pivoting, deferred diagonal scale)
    for (int p = 0; p < NO; ++p) {
      if (tid < NO) colp[tid] = Wgj[tid*GJS + p];
      __syncthreads();
      float rp = 1.f / colp[p];
      for (int o = tid; o < NO*NS; o += BLK) {
        int r = o >> 6, c = o & 63;
        if (r != p) Wgj[r*GJS + c] -= colp[r] * rp * Wgj[p*GJS + c];
      }
      __syncthreads();
    }
    // deferred scale: Pzinv[n][m] = W[n][32+m] / W[n][n]
    for (int o = tid; o < NO*NO; o += BLK) {
      int n2 = o >> 5, m = o & 31;
      Wgj[n2*GJS + NO + m] *= 1.f / Wgj[n2*GJS + n2];
    }
    __syncthreads();

    // ---- K = Pxz @ Pzinv (64 x 32)
    {
      int i = lane;
      float acc[8];
      #pragma unroll
      for (int q = 0; q < 8; ++q) acc[q] = 0.f;
      for (int n2 = 0; n2 < NO; ++n2) {
        float pv = Pxz[i*PXS + n2];
        #pragma unroll
        for (int q = 0; q < 8; ++q) acc[q] += pv * Wgj[n2*GJS + NO + (grp + 4*q)];
      }
      #pragma unroll
      for (int q = 0; q < 8; ++q) Km[i*PXS + (grp + 4*q)] = acc[q];
    }
    __syncthreads();

    // ---- innovation + x_new (wave0, lock-step) while all threads build M = K @ Pxz^T
    if (tid < NS) {
      if (tid < NO) {
        float z = 0.f;
        for (int jj = 0; jj < NS; ++jj) z += sH[tid*HS + jj] * sxp[jj];
        sinn[tid] = Yg[sbase*NO + tid] - z;
      }
      float xn = sxp[tid];
      for (int m = 0; m < NO; ++m) xn += Km[tid*PXS + m] * sinn[m];
      sx[tid] = xn;
      outX[sbase*NS + tid] = xn;
      float dd = xn - Xg[sbase*NS + tid];
      errAcc += dd*dd;
    }
    for (int o = tid; o < NS*NS; o += BLK) {  // M (overwrites GJ region; K phase done)
      int i = o >> 6, j = o & 63;
      float acc = 0.f;
      for (int m = 0; m < NO; ++m) acc += Km[i*PXS + m] * Pxz[j*PXS + m];
      Mb[i*GJS + j] = acc;
    }
    __syncthreads();

    // ---- P_new = Pn + Q - 0.5*(M + M^T); keep in P, write out
    for (int o = tid; o < NS*NS; o += BLK) {
      int i = o >> 6, j = o & 63;
      float v = P[i*PS + j] + Qg[o] - 0.5f*(Mb[i*GJS + j] + Mb[j*GJS + i]);
      P[i*PS + j] = v;
      outP[sbase*(size_t)(NS*NS) + o] = v;
    }
    __syncthreads();
  }

  // ---- per-trajectory squared-error total
  sPart[tid] = errAcc;
  __syncthreads();
  if (tid < 64) {
    float v = sPart[tid] + sPart[tid+64] + sPart[tid+128] + sPart[tid+192];
    for (int off = 32; off > 0; off >>= 1) v += __shfl_down(v, off);
    if (tid == 0) wsPart[traj] = v;
  }
}

__global__ __launch_bounds__(128)
void mse_reduce(const float* __restrict__ part, float* __restrict__ outS)
{
  __shared__ float sbuf[128];
  int tid = threadIdx.x;
  sbuf[tid] = part[tid];
  __syncthreads();
  if (tid < 64) {
    float v = sbuf[tid] + sbuf[tid + 64];
    for (int off = 32; off > 0; off >>= 1) v += __shfl_down(v, off);
    if (tid == 0) {
      float m = v / (128.f * 250.f * 64.f);
      outS[0] = m;
      outS[1] = 10.f * log10f(m);
    }
  }
}

extern "C" void kernel_launch(void* const* d_in, const int* in_sizes, int n_in,
                              void* d_out, int out_size, void* d_ws, size_t ws_size,
                              hipStream_t stream) {
  const float* Xg = (const float*)d_in[0];
  const float* Yg = (const float*)d_in[1];
  const float* Fg = (const float*)d_in[2];
  const float* Hg = (const float*)d_in[3];
  const float* Qg = (const float*)d_in[4];
  const float* Rg = (const float*)d_in[5];

  float* outX = (float*)d_out;                                   // 128*250*64
  float* outP = outX + (size_t)NTRAJ*TSTEPS*NS;                  // 128*250*64*64
  float* outS = outP + (size_t)NTRAJ*TSTEPS*NS*NS;               // 2 scalars
  float* wsP  = (float*)d_ws;                                    // 128 partials

  hipLaunchKernelGGL(ukf_main, dim3(NTRAJ), dim3(BLK), 0, stream,
                     Xg, Yg, Fg, Hg, Qg, Rg, outX, outP, wsP);
  hipLaunchKernelGGL(mse_reduce, dim3(1), dim3(128), 0, stream, wsP, outS);
}

// Round 2
// 11808.400 us; speedup vs baseline: 2.4606x; 2.4606x over previous
//
#include <hip/hip_runtime.h>
#include <math.h>

// UKF, one block per trajectory, 256 threads, all state in LDS.
// n=64 states, m=32 obs, T=250 steps, 128 trajectories.
// Weights: lam=-1, n+lam=63: Wm0=-1/63, Wc0=2-1/63, rest 0.5/63.
//
// R2: barrier count 140 -> 26 per step.
//  - Cholesky: panel-8 blocked; wave0 factors panel in registers (shfl), all
//    waves do rank-8 trailing update. 63 barriers -> 15.
//  - Pz inverse: fully in-register Gauss-Jordan on wave0 (lane = augmented
//    column, 32 VGPRs), zero inner barriers; wave1 does innovation, waves 2-3
//    do P += Q concurrently.
//  - dxs subtract fused into Pn tiles; x_pred partials fused into sigma loop;
//    M computed lower-triangle only (symmetric), wave3 does x_new in parallel.
//  - PS/GJS 66->65 (stride-1-bank: free 2-way), H transposed stride 36 for
//    float4 reads, phase-9 write swizzle. tanh via __expf.

#define NTRAJ 128
#define TSTEPS 250
#define NS 64
#define NO 32
#define PS 65    // P row stride: odd -> column access is free 2-way
#define SFS 68   // sigma buffer row stride: multiple of 4 -> float4 rows
#define HTS 36   // H^T row stride (row j holds H[:,j]), float4-aligned
#define PXS 33   // Pxz / K / Pzinv-colmajor row stride
#define GJS 65   // Pz / M stride
#define BLK 256

#define DTc 0.02f
#define W_C (0.5f/63.0f)
#define WM0 (-1.0f/63.0f)
#define WC0 (2.0f - 1.0f/63.0f)

__device__ __forceinline__ float tanh_fast(float x) {
  // tanh(x) = 1 - 2/(e^{2x}+1); handles +-inf saturation naturally.
  float e = __expf(2.0f * x);
  return 1.0f - 2.0f / (e + 1.0f);
}

__global__ __launch_bounds__(BLK)
void ukf_main(const float* __restrict__ Xg, const float* __restrict__ Yg,
              const float* __restrict__ Fg, const float* __restrict__ Hg,
              const float* __restrict__ Qg, const float* __restrict__ Rg,
              float* __restrict__ outX, float* __restrict__ outP,
              float* __restrict__ wsPart)
{
  __shared__ __align__(16) float P[NS*PS];      // 4160: P / chol L / Pn / P_new
  __shared__ __align__(16) float sfb[128*SFS];  // 8704: F^T + FL + sigma; overlaid below
  __shared__ __align__(16) float sHT[NS*HTS];   // 2304: H^T, persistent
  __shared__ float sPart[4*NS];                 // 256
  __shared__ float sx[NS], sxp[NS], sFx[NS], s0[NS];
  __shared__ float sinn[NO];

  float* Pxz = sfb;                 // [0,    2112): 64 x PXS
  float* Km  = sfb + NS*PXS;        // [2112, 4224): 64 x PXS
  float* Wgj = sfb + 2*NS*PXS;      // [4224, 6304): 32 x GJS (Pz); later Pzinv col-major 32 x PXS
  float* Mb  = sfb + 2*NS*PXS;      // [4224, 8384): 64 x GJS (M lower, after GJ dead)

  const int tid  = threadIdx.x;
  const int lane = tid & 63;
  const int grp  = tid >> 6;
  const int traj = blockIdx.x;

  // ---- one-time init: P = 1e-5*I, x = 0, stage H^T
  for (int o = tid; o < NS*NS; o += BLK) {
    int i = o >> 6, j = o & 63;
    P[i*PS + j] = (i == j) ? 1e-5f : 0.f;
  }
  for (int o = tid; o < NO*NS; o += BLK) {
    int m = o >> 6, j = o & 63;
    sHT[j*HTS + m] = Hg[o];
  }
  if (tid < NS) sx[tid] = 0.f;
  float errAcc = 0.f;
  __syncthreads();

  for (int t = 0; t < TSTEPS; ++t) {
    const size_t sbase = (size_t)traj*TSTEPS + t;

    // ---- phase 1: A = 63*(P + 1e-8 I) in place; stage F^T into sfb rows 0..63
    for (int o = tid; o < NS*NS; o += BLK) {
      int i = o >> 6, j = o & 63;
      float v = P[i*PS + j] * 63.f;
      if (i == j) v += 6.3e-7f;
      P[i*PS + j] = v;
      sfb[j*SFS + i] = Fg[o];     // FT[j][i] = F[i][j]
    }
    __syncthreads();

    // ---- Cholesky: panel-8 blocked, 15 barriers total
    for (int pc = 0; pc < NS; pc += 8) {
      if (grp == 0) {
        // wave0 factors the 64x8 panel in registers, lock-step
        const int i = lane;
        float pr[8];
        #pragma unroll
        for (int jj = 0; jj < 8; ++jj) pr[jj] = P[i*PS + pc + jj];
        #pragma unroll
        for (int jj = 0; jj < 8; ++jj) {
          const int gc = pc + jj;
          float dv  = __shfl(pr[jj], gc);   // updated diagonal
          float inv = rsqrtf(dv);
          float d   = dv * inv;
          pr[jj] = (i == gc) ? d : pr[jj] * inv;  // rows i<gc hold junk (upper) - harmless
          #pragma unroll
          for (int kk = jj + 1; kk < 8; ++kk) {
            float ck = __shfl(pr[jj], pc + kk);   // L[pc+kk][gc]
            pr[kk] = fmaf(-pr[jj], ck, pr[kk]);
          }
        }
        #pragma unroll
        for (int jj = 0; jj < 8; ++jj) P[i*PS + pc + jj] = pr[jj];
      }
      __syncthreads();
      if (pc < NS - 8) {
        // trailing rank-8 update: all waves; full column range (upper junk ok)
        const int i = lane;
        float Li[8];
        #pragma unroll
        for (int jj = 0; jj < 8; ++jj) Li[jj] = P[i*PS + pc + jj];
        for (int k = pc + 8 + grp; k < NS; k += 4) {
          float acc = P[i*PS + k];
          #pragma unroll
          for (int jj = 0; jj < 8; ++jj)
            acc = fmaf(-Li[jj], P[k*PS + pc + jj], acc);  // P[k][..] wave-uniform
          P[i*PS + k] = acc;
        }
        __syncthreads();
      }
    }

    // ---- FL = F @ L into sfb rows 64..127 (row 64+c holds FL[:,c]); Fx by wave0
    {
      const int c0 = (tid >> 4) << 2;
      const int j0 = (tid & 15) << 2;
      float acc[4][4];
      #pragma unroll
      for (int a = 0; a < 4; ++a)
        #pragma unroll
        for (int b = 0; b < 4; ++b) acc[a][b] = 0.f;
      for (int jj = 0; jj < NS; ++jj) {
        float4 fv = *(const float4*)&sfb[jj*SFS + j0];  // F[j0..j0+3][jj]
        float lv[4];
        #pragma unroll
        for (int a = 0; a < 4; ++a) {
          int cc = c0 + a;
          lv[a] = (jj >= cc) ? P[jj*PS + cc] : 0.f;     // L[jj][cc]
        }
        #pragma unroll
        for (int a = 0; a < 4; ++a) {
          acc[a][0] = fmaf(lv[a], fv.x, acc[a][0]);
          acc[a][1] = fmaf(lv[a], fv.y, acc[a][1]);
          acc[a][2] = fmaf(lv[a], fv.z, acc[a][2]);
          acc[a][3] = fmaf(lv[a], fv.w, acc[a][3]);
        }
      }
      #pragma unroll
      for (int a = 0; a < 4; ++a) {
        float4 w4; w4.x = acc[a][0]; w4.y = acc[a][1]; w4.z = acc[a][2]; w4.w = acc[a][3];
        *(float4*)&sfb[(64 + c0 + a)*SFS + j0] = w4;    // FL[j][c] at sfb[64+c][j]
      }
    }
    if (tid < NS) {            // Fx = F @ x (reads FT rows)
      float a2 = 0.f;
      for (int jj = 0; jj < NS; ++jj) a2 = fmaf(sfb[jj*SFS + tid], sx[jj], a2);
      sFx[tid] = a2;
    }
    __syncthreads();

    // ---- sigma points + fused x_pred partial sums. rows 0..63 plus, 64..127 minus
    {
      const int j = lane;
      float psum = 0.f;
      float xv = sx[j], fxv = sFx[j];
      for (int cc = grp; cc < NS; cc += 4) {
        float flv = sfb[(64+cc)*SFS + j];
        float Lv  = (j >= cc) ? P[j*PS + cc] : 0.f;
        float vp = xv + Lv + DTc * tanh_fast(fxv + flv);
        float vm = xv - Lv + DTc * tanh_fast(fxv - flv);
        sfb[cc*SFS + j]      = vp;
        sfb[(64+cc)*SFS + j] = vm;
        psum += vp + vm;
      }
      sPart[grp*NS + j] = psum;
    }
    if (tid < NS) s0[tid] = sx[tid] + DTc * tanh_fast(sFx[tid]);
    __syncthreads();

    // ---- combine -> x_pred, center deviation
    if (tid < NS) {
      float xp = fmaf(W_C, sPart[tid] + sPart[NS+tid] + sPart[2*NS+tid] + sPart[3*NS+tid],
                      WM0 * s0[tid]);
      sxp[tid] = xp;
      s0[tid] -= xp;
    }
    __syncthreads();

    // ---- Pn = Wc0*d0 d0^T + c*sum (sf-x)(sf-x)^T -> P  (subtract fused in registers)
    {
      const int i0 = (tid >> 4) << 2;
      const int j0 = (tid & 15) << 2;
      float acc[4][4];
      #pragma unroll
      for (int a = 0; a < 4; ++a)
        #pragma unroll
        for (int b = 0; b < 4; ++b) acc[a][b] = 0.f;
      float xi[4], xj[4];
      #pragma unroll
      for (int a = 0; a < 4; ++a) { xi[a] = sxp[i0+a]; xj[a] = sxp[j0+a]; }
      for (int r = 0; r < 128; ++r) {
        float4 av = *(const float4*)&sfb[r*SFS + i0];
        float4 bv = *(const float4*)&sfb[r*SFS + j0];
        float da[4] = {av.x - xi[0], av.y - xi[1], av.z - xi[2], av.w - xi[3]};
        float db[4] = {bv.x - xj[0], bv.y - xj[1], bv.z - xj[2], bv.w - xj[3]};
        #pragma unroll
        for (int a = 0; a < 4; ++a)
          #pragma unroll
          for (int b = 0; b < 4; ++b) acc[a][b] = fmaf(da[a], db[b], acc[a][b]);
      }
      const int rot = (i0 >> 2) & 3;   // write swizzle: spread banks
      #pragma unroll
      for (int a = 0; a < 4; ++a) {
        float d0a = s0[i0+a];
        #pragma unroll
        for (int b = 0; b < 4; ++b) {
          int bb = (b + rot) & 3;
          P[(i0+a)*PS + j0 + bb] = fmaf(WC0 * d0a, s0[j0+bb], W_C * acc[a][bb]);
        }
      }
    }
    __syncthreads();

    // ---- Pxz = Pn @ H^T (64 x 32), float4 H^T reads
    {
      const int i = lane;
      const int cb = grp * 8;
      float acc[8];
      #pragma unroll
      for (int u = 0; u < 8; ++u) acc[u] = 0.f;
      for (int jj = 0; jj < NS; ++jj) {
        float pv = P[i*PS + jj];
        float4 h0 = *(const float4*)&sHT[jj*HTS + cb];
        float4 h1 = *(const float4*)&sHT[jj*HTS + cb + 4];
        acc[0] = fmaf(pv, h0.x, acc[0]); acc[1] = fmaf(pv, h0.y, acc[1]);
        acc[2] = fmaf(pv, h0.z, acc[2]); acc[3] = fmaf(pv, h0.w, acc[3]);
        acc[4] = fmaf(pv, h1.x, acc[4]); acc[5] = fmaf(pv, h1.y, acc[5]);
        acc[6] = fmaf(pv, h1.z, acc[6]); acc[7] = fmaf(pv, h1.w, acc[7]);
      }
      #pragma unroll
      for (int u = 0; u < 8; ++u) Pxz[i*PXS + cb + u] = acc[u];
    }
    __syncthreads();

    // ---- Pz = H @ Pxz + R (32 x 32) into Wgj
    {
      const int m = tid >> 3;
      const int n0 = tid & 7;
      float acc[4];
      #pragma unroll
      for (int q = 0; q < 4; ++q) acc[q] = Rg[m*NO + n0 + 8*q];
      for (int i2 = 0; i2 < NS; ++i2) {
        float hv = sHT[i2*HTS + m];
        #pragma unroll
        for (int q = 0; q < 4; ++q)
          acc[q] = fmaf(hv, Pxz[i2*PXS + n0 + 8*q], acc[q]);
      }
      #pragma unroll
      for (int q = 0; q < 4; ++q) Wgj[m*GJS + n0 + 8*q] = acc[q];
    }
    __syncthreads();

    // ---- wave0: in-register Gauss-Jordan inverse of Pz (zero barriers)
    //      wave1: innovation; waves 2,3: P += Q
    if (grp == 0) {
      const int c = lane;                 // augmented column [Pz | I]
      float w[NO];
      #pragma unroll
      for (int r = 0; r < NO; ++r)
        w[r] = (c < NO) ? Wgj[r*GJS + c] : ((c - NO == r) ? 1.f : 0.f);
      #pragma unroll
      for (int p = 0; p < NO; ++p) {
        float piv = __shfl(w[p], p);
        float rp  = 1.0f / piv;
        float wp  = w[p] * rp;            // normalized pivot-row element
        #pragma unroll
        for (int r = 0; r < NO; ++r) {
          if (r == p) continue;
          float cr = __shfl(w[r], p);     // column-p value (pre-update)
          w[r] = fmaf(-cr, wp, w[r]);
        }
        w[p] = wp;
      }
      if (c >= NO) {                       // Pzinv col-major: [col][row], stride PXS
        #pragma unroll
        for (int r = 0; r < NO; ++r) Wgj[(c - NO)*PXS + r] = w[r];
      }
    } else if (grp == 1) {
      if (lane < NO) {
        float z = 0.f;
        for (int jj = 0; jj < NS; ++jj) z = fmaf(sHT[jj*HTS + lane], sxp[jj], z);
        sinn[lane] = Yg[sbase*NO + lane] - z;
      }
    } else {
      for (int o = tid - 128; o < NS*NS; o += 128) {
        int i = o >> 6, j = o & 63;
        P[i*PS + j] += Qg[o];
      }
    }
    __syncthreads();

    // ---- K = Pxz @ Pzinv (64 x 32)
    {
      const int i = lane;
      const int cb = grp * 8;
      float acc[8];
      #pragma unroll
      for (int u = 0; u < 8; ++u) acc[u] = 0.f;
      for (int n2 = 0; n2 < NO; ++n2) {
        float pv = Pxz[i*PXS + n2];
        #pragma unroll
        for (int u = 0; u < 8; ++u)
          acc[u] = fmaf(pv, Wgj[(cb + u)*PXS + n2], acc[u]);  // wave-uniform reads
      }
      #pragma unroll
      for (int u = 0; u < 8; ++u) Km[i*PXS + cb + u] = acc[u];
    }
    __syncthreads();

    // ---- M = K @ Pxz^T, lower-triangle 4x4 tiles (tid<136); wave3: x_new + err
    if (tid < 136) {
      int r = (int)((sqrtf(8.f*(float)tid + 1.f) - 1.f) * 0.5f);
      while ((r+1)*(r+2)/2 <= tid) ++r;
      while (r*(r+1)/2 > tid) --r;
      const int c2 = tid - ((r*(r+1)) >> 1);
      const int i0 = r << 2, j0 = c2 << 2;
      float acc[4][4];
      #pragma unroll
      for (int a = 0; a < 4; ++a)
        #pragma unroll
        for (int b = 0; b < 4; ++b) acc[a][b] = 0.f;
      for (int m = 0; m < NO; ++m) {
        float ka[4], pb[4];
        #pragma unroll
        for (int a = 0; a < 4; ++a) ka[a] = Km[(i0+a)*PXS + m];
        #pragma unroll
        for (int b = 0; b < 4; ++b) pb[b] = Pxz[(j0+b)*PXS + m];
        #pragma unroll
        for (int a = 0; a < 4; ++a)
          #pragma unroll
          for (int b = 0; b < 4; ++b) acc[a][b] = fmaf(ka[a], pb[b], acc[a][b]);
      }
      #pragma unroll
      for (int a = 0; a < 4; ++a)
        #pragma unroll
        for (int b = 0; b < 4; ++b) Mb[(i0+a)*GJS + j0 + b] = acc[a][b];
    } else if (tid >= 192) {
      const int i = tid - 192;
      float xn = sxp[i];
      #pragma unroll 8
      for (int m = 0; m < NO; ++m) xn = fmaf(Km[i*PXS + m], sinn[m], xn);
      sx[i] = xn;
      outX[sbase*NS + i] = xn;
      float dd = xn - Xg[sbase*NS + i];
      errAcc = fmaf(dd, dd, errAcc);
    }
    __syncthreads();

    // ---- P_new = (Pn + Q) - M_sym; keep in P, write out
    for (int o = tid; o < NS*NS; o += BLK) {
      int i = o >> 6, j = o & 63;
      float mv = (i >= j) ? Mb[i*GJS + j] : Mb[j*GJS + i];
      float v = P[i*PS + j] - mv;
      P[i*PS + j] = v;
      outP[sbase*(size_t)(NS*NS) + o] = v;
    }
    __syncthreads();
  }

  // ---- per-trajectory squared-error total
  sPart[tid] = errAcc;
  __syncthreads();
  if (tid < 64) {
    float v = sPart[tid] + sPart[tid+64] + sPart[tid+128] + sPart[tid+192];
    for (int off = 32; off > 0; off >>= 1) v += __shfl_down(v, off);
    if (tid == 0) wsPart[traj] = v;
  }
}

__global__ __launch_bounds__(128)
void mse_reduce(const float* __restrict__ part, float* __restrict__ outS)
{
  __shared__ float sbuf[128];
  int tid = threadIdx.x;
  sbuf[tid] = part[tid];
  __syncthreads();
  if (tid < 64) {
    float v = sbuf[tid] + sbuf[tid + 64];
    for (int off = 32; off > 0; off >>= 1) v += __shfl_down(v, off);
    if (tid == 0) {
      float m = v / (128.f * 250.f * 64.f);
      outS[0] = m;
      outS[1] = 10.f * log10f(m);
    }
  }
}

extern "C" void kernel_launch(void* const* d_in, const int* in_sizes, int n_in,
                              void* d_out, int out_size, void* d_ws, size_t ws_size,
                              hipStream_t stream) {
  const float* Xg = (const float*)d_in[0];
  const float* Yg = (const float*)d_in[1];
  const float* Fg = (const float*)d_in[2];
  const float* Hg = (const float*)d_in[3];
  const float* Qg = (const float*)d_in[4];
  const float* Rg = (const float*)d_in[5];

  float* outX = (float*)d_out;                                   // 128*250*64
  float* outP = outX + (size_t)NTRAJ*TSTEPS*NS;                  // 128*250*64*64
  float* outS = outP + (size_t)NTRAJ*TSTEPS*NS*NS;               // 2 scalars
  float* wsP  = (float*)d_ws;                                    // 128 partials

  hipLaunchKernelGGL(ukf_main, dim3(NTRAJ), dim3(BLK), 0, stream,
                     Xg, Yg, Fg, Hg, Qg, Rg, outX, outP, wsP);
  hipLaunchKernelGGL(mse_reduce, dim3(1), dim3(128), 0, stream, wsP, outS);
}